// Round 10
// baseline (47.458 us; speedup 1.0000x reference)
//
#include <hip/hip_runtime.h>
#include <hip/hip_bf16.h>

// Shapes
#define B_ 64
#define L_ 64
#define D_ 512
#define F_ 32
#define H_ 512
#define M_ROWS 2048
#define KA 1024

typedef __attribute__((ext_vector_type(8))) short bf16x8;
typedef __attribute__((ext_vector_type(4))) float f32x4;

__device__ __forceinline__ float leaky(float v) { return v > 0.0f ? v : 0.01f * v; }

__device__ __forceinline__ unsigned short f2bf(float v) {
  unsigned int b = __float_as_uint(v);
  unsigned int r = b + 0x7FFF + ((b >> 16) & 1);  // RNE
  return (unsigned short)(r >> 16);
}
__device__ __forceinline__ float bf2f(unsigned short h) {
  return __uint_as_float(((unsigned int)h) << 16);
}
__device__ __forceinline__ void cvt_store4(unsigned short* ph, unsigned short* pl, float4 v) {
  ushort4 h, l;
  h.x = f2bf(v.x); l.x = f2bf(v.x - bf2f(h.x));
  h.y = f2bf(v.y); l.y = f2bf(v.y - bf2f(h.y));
  h.z = f2bf(v.z); l.z = f2bf(v.z - bf2f(h.z));
  h.w = f2bf(v.w); l.w = f2bf(v.w - bf2f(h.w));
  *(ushort4*)ph = h;
  *(ushort4*)pl = l;
}

#define GLOAD16(GP, LP)                                              \
  __builtin_amdgcn_global_load_lds(                                  \
      (const __attribute__((address_space(1))) unsigned int*)(GP),   \
      (__attribute__((address_space(3))) unsigned int*)(LP), 16, 0, 0)

// ---------------- Kernel 1: prep ----------------
// blocks [0,512):    x-split flat -> Xhi/Xlo [4096][512]
// blocks [512,768):  w-split: W0t & W1t, both [512 n][1024 k] hi/lo
//                    (k<512 = self-W rows, k>=512 = aggr-W rows)
// blocks [768,1024): means: q=blk-768, b=q>>2, chunk cc=q&3 (128 cols):
//                    LDS histogram -> exact count matrix C[48][64] (counts/32)
//                    -> MFMA M = C @ (xh + xl) -> split-store Mh/Ml [b][48][512]
__global__ __launch_bounds__(256) void prep(
    const float* __restrict__ x, const int* __restrict__ idx1,
    const int* __restrict__ idx2,
    const float* __restrict__ Ws0, const float* __restrict__ Wa0,
    const float* __restrict__ Ws1, const float* __restrict__ Wa1,
    unsigned short* __restrict__ Xhi, unsigned short* __restrict__ Xlo,
    unsigned short* __restrict__ W0thi, unsigned short* __restrict__ W0tlo,
    unsigned short* __restrict__ W1thi, unsigned short* __restrict__ W1tlo,
    unsigned short* __restrict__ Mh, unsigned short* __restrict__ Ml) {
  __shared__ __align__(16) char smem[51456];
  const int blk = blockIdx.x;
  const int t = threadIdx.x;

  if (blk < 512) {
    // ---- x-split: 512 x 256 x 4 float4
    const int base = blk * 256 + t;
#pragma unroll
    for (int i = 0; i < 4; ++i) {
      const int f4 = base + i * 131072;
      const float4 v = *(const float4*)(x + (size_t)f4 * 4);
      cvt_store4(Xhi + (size_t)f4 * 4, Xlo + (size_t)f4 * 4, v);
    }
  } else if (blk < 768) {
    // ---- weight transpose+split into [512 n][1024 k]
    float (*lt)[72] = (float(*)[72])smem;
    const int q = blk - 512;          // 0..255; 128 per cat
    const int cat = q >> 7;           // 0: W0, 1: W1
    const int qq = q & 127;
    const int k0 = (qq & 15) * 64;    // k in [0,1024)
    const int n0 = (qq >> 4) * 64;    // n in [0,512)
    const float* src = (cat == 0)
        ? ((k0 < 512) ? Ws0 + (size_t)k0 * H_ : Wa0 + (size_t)(k0 - 512) * H_)
        : ((k0 < 512) ? Ws1 + (size_t)k0 * H_ : Wa1 + (size_t)(k0 - 512) * H_);
    unsigned short* dhi = (cat == 0) ? W0thi : W1thi;
    unsigned short* dlo = (cat == 0) ? W0tlo : W1tlo;
#pragma unroll
    for (int i = 0; i < 4; ++i) {
      const int idx4 = t + 256 * i;
      const int kl = idx4 >> 4;
      const int n4 = (idx4 & 15) * 4;
      *(float4*)&lt[kl][n4] = *(const float4*)(src + (size_t)kl * H_ + n0 + n4);
    }
    __syncthreads();
#pragma unroll
    for (int i = 0; i < 4; ++i) {
      const int idx4 = t + 256 * i;
      const int nl = idx4 >> 4;
      const int k4 = (idx4 & 15) * 4;
      ushort4 h, l;
      const float v0 = lt[k4 + 0][nl], v1 = lt[k4 + 1][nl];
      const float v2 = lt[k4 + 2][nl], v3 = lt[k4 + 3][nl];
      h.x = f2bf(v0); l.x = f2bf(v0 - bf2f(h.x));
      h.y = f2bf(v1); l.y = f2bf(v1 - bf2f(h.y));
      h.z = f2bf(v2); l.z = f2bf(v2 - bf2f(h.z));
      h.w = f2bf(v3); l.w = f2bf(v3 - bf2f(h.w));
      *(ushort4*)(dhi + (size_t)(n0 + nl) * KA + k0 + k4) = h;
      *(ushort4*)(dlo + (size_t)(n0 + nl) * KA + k0 + k4) = l;
    }
  } else {
    // ---- means: per (b, 128-col chunk)
    const int q = blk - 768;
    const int b = q >> 2;
    const int cc = q & 3;
    unsigned int* cnt = (unsigned int*)smem;                  // [33][64] @0 (8448B)
    unsigned short* Cbf = (unsigned short*)(smem + 8448);     // [48][64] (6144B)
    unsigned short* XTh = (unsigned short*)(smem + 14592);    // [128][72] (18432B)
    unsigned short* XTl = (unsigned short*)(smem + 33024);    // [128][72]
    const int lane = t & 63;
    const int w = t >> 6;
    const int lr = lane & 15;
    const int kb = lane >> 4;

#pragma unroll
    for (int i = 0; i < 9; ++i) { const int p = t + 256 * i; if (p < 2112) cnt[p] = 0u; }
    __syncthreads();
#pragma unroll
    for (int i = 0; i < 4; ++i) {
      const int j = t + 256 * i;  // 0..1023, f = j>>5
      atomicAdd(&cnt[(j >> 5) * 64 + idx2[(size_t)b * 1024 + j]], 1u);
    }
    if (t < 32) atomicAdd(&cnt[32 * 64 + idx1[b * F_ + t]], 1u);
    __syncthreads();
    // exact bf16 count matrix (counts/32) + x^T chunk staged hi/lo
#pragma unroll
    for (int i = 0; i < 12; ++i) {
      const int p = t + 256 * i;  // 0..3071
      Cbf[p] = (p < 2112) ? f2bf((float)cnt[p] * 0.03125f) : (unsigned short)0;
    }
#pragma unroll
    for (int i = 0; i < 8; ++i) {
      const int idx4 = t + 256 * i;        // 0..2047 float4 of the 64x128 chunk
      const int l = idx4 >> 5;             // 0..63
      const int c4 = (idx4 & 31) * 4;      // 0..124
      const float4 v = *(const float4*)(x + (size_t)b * (L_ * D_) + (size_t)l * D_ + cc * 128 + c4);
      unsigned short h;
      h = f2bf(v.x); XTh[(c4 + 0) * 72 + l] = h; XTl[(c4 + 0) * 72 + l] = f2bf(v.x - bf2f(h));
      h = f2bf(v.y); XTh[(c4 + 1) * 72 + l] = h; XTl[(c4 + 1) * 72 + l] = f2bf(v.y - bf2f(h));
      h = f2bf(v.z); XTh[(c4 + 2) * 72 + l] = h; XTl[(c4 + 2) * 72 + l] = f2bf(v.z - bf2f(h));
      h = f2bf(v.w); XTh[(c4 + 3) * 72 + l] = h; XTl[(c4 + 3) * 72 + l] = f2bf(v.w - bf2f(h));
    }
    __syncthreads();

    // MFMA: M[48][128-chunk] = C @ (xh + xl); wave w owns cols w*32..+31
    f32x4 acc[3][2] = {};
#pragma unroll
    for (int kf = 0; kf < 2; ++kf) {
#pragma unroll
      for (int ni = 0; ni < 2; ++ni) {
        const int coll = w * 32 + ni * 16 + lr;
        const bf16x8 Bh = *(const bf16x8*)&XTh[coll * 72 + kf * 32 + kb * 8];
        const bf16x8 Bl = *(const bf16x8*)&XTl[coll * 72 + kf * 32 + kb * 8];
#pragma unroll
        for (int mi = 0; mi < 3; ++mi) {
          const bf16x8 Af = *(const bf16x8*)&Cbf[(mi * 16 + lr) * 64 + kf * 32 + kb * 8];
          acc[mi][ni] = __builtin_amdgcn_mfma_f32_16x16x32_bf16(Af, Bh, acc[mi][ni], 0, 0, 0);
          acc[mi][ni] = __builtin_amdgcn_mfma_f32_16x16x32_bf16(Af, Bl, acc[mi][ni], 0, 0, 0);
        }
      }
    }
    // C/D layout: col = lane&15, row = kb*4 + r (+ mi*16). Keep rows <= 32.
#pragma unroll
    for (int mi = 0; mi < 3; ++mi)
#pragma unroll
      for (int ni = 0; ni < 2; ++ni)
#pragma unroll
        for (int r = 0; r < 4; ++r) {
          const int row48 = mi * 16 + kb * 4 + r;
          if (row48 > 32) continue;
          const int col = cc * 128 + w * 32 + ni * 16 + lr;
          const float v = acc[mi][ni][r];
          const unsigned short h = f2bf(v);
          Mh[((size_t)b * 48 + row48) * 512 + col] = h;
          Ml[((size_t)b * 48 + row48) * 512 + col] = f2bf(v - bf2f(h));
        }
  }
}

// ---------------- Kernel 2: gathered MFMA GEMM (R7 structure) ---------------
// C = [f1|m] @ W0t^T, 3-term hi/lo. BM=64 BN=32 BK=64, 4 waves, dbuf LDS,
// 528 blocks XCD-chunk-swizzled. M layout [b][48][512] via per-lane mrow.
__global__ __launch_bounds__(256) void gemm1(
    const unsigned short* __restrict__ Xhi, const unsigned short* __restrict__ Xlo,
    const unsigned short* __restrict__ Mh, const unsigned short* __restrict__ Ml,
    const unsigned short* __restrict__ Wthi, const unsigned short* __restrict__ Wtlo,
    const int* __restrict__ idx1, const float* __restrict__ b0,
    unsigned short* __restrict__ Hhi, unsigned short* __restrict__ Hlo) {
  __shared__ unsigned short lds[24576];  // 48 KB
  const int tid = threadIdx.x;
  const int lane = tid & 63;
  const int w = tid >> 6;
  const int wr = w >> 1, wc = w & 1;
  const int lr = lane & 15;
  const int kb = lane >> 4;
  const int swz = lr & 7;
  const int rsel = lane >> 3;
  const int cbs = ((lane & 7) ^ rsel) * 8;

  const int o = blockIdx.x;
  const int s = (o & 7) * 66 + (o >> 3);  // 528 = 8 XCDs * 66
  const int bmi = s >> 4;                 // 0..32
  const int bni = s & 15;
  const int bm = bmi * 64;
  const int bn = bni * 32;

  int xrow[8], mrow[8];
  if (w < 2) {
#pragma unroll
    for (int i = 0; i < 8; ++i) {
      const int R = bm + rsel + 8 * i;
      if (bmi < 32) {
        xrow[i] = (R >> 5) * 64 + idx1[R];
        mrow[i] = (R >> 5) * 48 + (R & 31);
      } else {
        const int bb = R - M_ROWS;
        xrow[i] = bb * 64;        // f0 row
        mrow[i] = bb * 48 + 32;   // m0 row
      }
    }
  }
  const unsigned short* Xp = (w == 0) ? Xhi : Xlo;
  const unsigned short* Mp = (w == 0) ? Mh : Ml;
  const unsigned short* Wp = (w == 2) ? Wthi : Wtlo;
  const unsigned short* wbase = Wp + (size_t)(bn + rsel) * KA + cbs;
  const int PB = (w == 0) ? 0 : (w == 1) ? 4096 : (w == 2) ? 8192 : 10240;

#define STAGE(KT, BUF)                                                        \
  {                                                                           \
    unsigned short* ldst = &lds[(BUF)*12288 + PB];                            \
    if (w < 2) {                                                              \
      if ((KT) < 8) {                                                         \
        const int co = (KT)*64 + cbs;                                         \
        _Pragma("unroll") for (int i = 0; i < 8; ++i)                         \
            GLOAD16(Xp + (size_t)xrow[i] * 512 + co, ldst + i * 512);         \
      } else {                                                                \
        const int co = ((KT)-8) * 64 + cbs;                                   \
        _Pragma("unroll") for (int i = 0; i < 8; ++i)                         \
            GLOAD16(Mp + (size_t)mrow[i] * 512 + co, ldst + i * 512);         \
      }                                                                       \
    } else {                                                                  \
      const unsigned short* wb = wbase + (KT)*64;                             \
      _Pragma("unroll") for (int i = 0; i < 4; ++i)                           \
          GLOAD16(wb + (size_t)i * 8 * KA, ldst + i * 512);                   \
    }                                                                         \
  }

  f32x4 acc[2] = {};
  STAGE(0, 0);
  __syncthreads();

#define AFRAG(PL, ROW, CB) \
  (*(const bf16x8*)&lds[buf * 12288 + (PL)*4096 + (ROW)*64 + (((CB) ^ swz) * 8)])
#define BFRAG(PL, ROW, CB) \
  (*(const bf16x8*)&lds[buf * 12288 + 8192 + (PL)*2048 + (ROW)*64 + (((CB) ^ swz) * 8)])

  for (int kt = 0; kt < 16; ++kt) {
    const int buf = kt & 1;
    if (kt < 15) STAGE(kt + 1, buf ^ 1);
#pragma unroll
    for (int ks = 0; ks < 2; ++ks) {
      const int c = ks * 4 + kb;
      const bf16x8 Ah0 = AFRAG(0, wr * 32 + lr, c);
      const bf16x8 Ah1 = AFRAG(0, wr * 32 + 16 + lr, c);
      const bf16x8 Al0 = AFRAG(1, wr * 32 + lr, c);
      const bf16x8 Al1 = AFRAG(1, wr * 32 + 16 + lr, c);
      const bf16x8 Bh = BFRAG(0, wc * 16 + lr, c);
      const bf16x8 Bl = BFRAG(1, wc * 16 + lr, c);
      acc[0] = __builtin_amdgcn_mfma_f32_16x16x32_bf16(Ah0, Bh, acc[0], 0, 0, 0);
      acc[0] = __builtin_amdgcn_mfma_f32_16x16x32_bf16(Ah0, Bl, acc[0], 0, 0, 0);
      acc[0] = __builtin_amdgcn_mfma_f32_16x16x32_bf16(Al0, Bh, acc[0], 0, 0, 0);
      acc[1] = __builtin_amdgcn_mfma_f32_16x16x32_bf16(Ah1, Bh, acc[1], 0, 0, 0);
      acc[1] = __builtin_amdgcn_mfma_f32_16x16x32_bf16(Ah1, Bl, acc[1], 0, 0, 0);
      acc[1] = __builtin_amdgcn_mfma_f32_16x16x32_bf16(Al1, Bh, acc[1], 0, 0, 0);
    }
    __syncthreads();
  }
#undef AFRAG
#undef BFRAG
#undef STAGE

  // Epilogue. C/D: col = lane&15, row = (lane>>4)*4 + reg.
  const int col = bn + wc * 16 + lr;
  const float bias = b0[col];
  if (bmi < 32) {
    const int b = bmi * 2 + wr;
    float sum = 0.f;
#pragma unroll
    for (int mi = 0; mi < 2; ++mi)
#pragma unroll
      for (int r = 0; r < 4; ++r) sum += leaky(acc[mi][r] + bias);
    sum += __shfl_xor(sum, 16);
    sum += __shfl_xor(sum, 32);
    sum *= (1.0f / 32.0f);
    if (lane < 16) {
      const unsigned short h = f2bf(sum);
      Hhi[(size_t)b * KA + 512 + col] = h;
      Hlo[(size_t)b * KA + 512 + col] = f2bf(sum - bf2f(h));
    }
  } else {
#pragma unroll
    for (int mi = 0; mi < 2; ++mi)
#pragma unroll
      for (int r = 0; r < 4; ++r) {
        const int b = wr * 32 + mi * 16 + kb * 4 + r;
        const float v = leaky(acc[mi][r] + bias);
        const unsigned short h = f2bf(v);
        Hhi[(size_t)b * KA + col] = h;
        Hlo[(size_t)b * KA + col] = f2bf(v - bf2f(h));
      }
  }
}

// ---------------- Kernel 3: gemm2 + bias + reduce (R9) ----------------------
__global__ __launch_bounds__(512) void gemm2f(
    const unsigned short* __restrict__ Hhi, const unsigned short* __restrict__ Hlo,
    const unsigned short* __restrict__ Wthi, const unsigned short* __restrict__ Wtlo,
    const float* __restrict__ b1, float* __restrict__ out) {
  __shared__ float sacc[8][1088];
  const int tid = threadIdx.x;
  const int w = tid >> 6;
  const int lane = tid & 63;
  const int lr = lane & 15;
  const int kb = lane >> 4;
  const int n0 = blockIdx.x * 16;
  const int kc = w * 128;

  f32x4 acc[4] = {};
#pragma unroll
  for (int ks = 0; ks < 4; ++ks) {
    const int k = kc + ks * 32 + kb * 8;
    const bf16x8 Bh = *(const bf16x8*)(Wthi + (size_t)(n0 + lr) * KA + k);
    const bf16x8 Bl = *(const bf16x8*)(Wtlo + (size_t)(n0 + lr) * KA + k);
#pragma unroll
    for (int mi = 0; mi < 4; ++mi) {
      const bf16x8 Ah = *(const bf16x8*)(Hhi + (size_t)(mi * 16 + lr) * KA + k);
      const bf16x8 Al = *(const bf16x8*)(Hlo + (size_t)(mi * 16 + lr) * KA + k);
      acc[mi] = __builtin_amdgcn_mfma_f32_16x16x32_bf16(Ah, Bh, acc[mi], 0, 0, 0);
      acc[mi] = __builtin_amdgcn_mfma_f32_16x16x32_bf16(Ah, Bl, acc[mi], 0, 0, 0);
      acc[mi] = __builtin_amdgcn_mfma_f32_16x16x32_bf16(Al, Bh, acc[mi], 0, 0, 0);
    }
  }
#pragma unroll
  for (int mi = 0; mi < 4; ++mi)
#pragma unroll
    for (int r = 0; r < 4; ++r)
      sacc[w][(mi * 16 + kb * 4 + r) * 17 + lr] = acc[mi][r];
  __syncthreads();

#pragma unroll
  for (int q = 0; q < 2; ++q) {
    const int oid = tid * 2 + q;
    const int row = oid >> 4;
    const int col = oid & 15;
    float sv = b1[n0 + col];
#pragma unroll
    for (int w2 = 0; w2 < 8; ++w2) sv += sacc[w2][row * 17 + col];
    out[(size_t)row * H_ + n0 + col] = sv;
  }
}

extern "C" void kernel_launch(void* const* d_in, const int* in_sizes, int n_in,
                              void* d_out, int out_size, void* d_ws, size_t ws_size,
                              hipStream_t stream) {
  const float* x    = (const float*)d_in[0];
  const int*   idx1 = (const int*)d_in[1];
  const int*   idx2 = (const int*)d_in[2];
  const float* Wa0  = (const float*)d_in[3];
  const float* b0   = (const float*)d_in[4];
  const float* Ws0  = (const float*)d_in[5];
  const float* Wa1  = (const float*)d_in[6];
  const float* b1   = (const float*)d_in[7];
  const float* Ws1  = (const float*)d_in[8];
  float* out = (float*)d_out;

  unsigned short* wsu = (unsigned short*)d_ws;
  unsigned short* Xhi   = wsu;                          // 4096*512
  unsigned short* Xlo   = Xhi + (size_t)4096 * 512;
  unsigned short* W0thi = Xlo + (size_t)4096 * 512;     // [512][1024]
  unsigned short* W0tlo = W0thi + (size_t)H_ * KA;
  unsigned short* W1thi = W0tlo + (size_t)H_ * KA;      // [512][1024]
  unsigned short* W1tlo = W1thi + (size_t)H_ * KA;
  unsigned short* Mhp   = W1tlo + (size_t)H_ * KA;      // [64][48][512]
  unsigned short* Mlp   = Mhp + (size_t)64 * 48 * 512;
  unsigned short* Hhi   = Mlp + (size_t)64 * 48 * 512;  // [64][1024]
  unsigned short* Hlo   = Hhi + (size_t)B_ * KA;

  prep<<<1024, 256, 0, stream>>>(x, idx1, idx2, Ws0, Wa0, Ws1, Wa1,
                                 Xhi, Xlo, W0thi, W0tlo, W1thi, W1tlo, Mhp, Mlp);
  gemm1<<<528, 256, 0, stream>>>(Xhi, Xlo, Mhp, Mlp, W0thi, W0tlo,
                                 idx1, b0, Hhi, Hlo);
  gemm2f<<<32, 512, 0, stream>>>(Hhi, Hlo, W1thi, W1tlo, b1, out);
}